// Round 2
// 246.167 us; speedup vs baseline: 1.0255x; 1.0255x over previous
//
#include <hip/hip_runtime.h>

// NeighbourCovariance: per vertex v, gather K=40 neighbors, weight features by
// exp(-10*distsq), compute per-feature weighted mean (C=3) and covariance (3x3).
// Output layout per vertex: [cov (F*9)] ++ [means (F*3)] = 384 floats.
//
// R4 = R3 with compile fix: __builtin_nontemporal_store requires a clang
// ext_vector_type, not HIP's float4 class. Structure unchanged:
//  Phase 1: block-cooperative. 320 (v,k) pairs per block; coalesced NT loads of
//           nidx/distsq (single-use streams -> keep out of L2/L3), ONE exp per
//           pair, coord gather (coords cacheable: 1.2 MB), stage (w,x,y,z) +
//           feature offset in LDS. Invalid neighbors stored as w=0.
//  Phase 2: lane = (vertex, feature). Inner loop: broadcast LDS read + one
//           coalesced 128B feature-row gather (12.8 MB, L3-resident once the
//           streams bypass) + 13 VALU.
//  Phase 3: results staged in LDS (12 KB/block), then written out fully
//           coalesced as 16B NON-TEMPORAL stores (3 dwordx4-nt per thread
//           instead of 12 scattered scalar stores), keeping the 150 MB write
//           stream from thrashing the Infinity Cache that holds the gather set.
//
// LDS: 5120 (wxyz) + 1280 (joff) + 12288 (out stage) = 18688 B/block
//      -> 8 blocks/CU (149.5 KB of 160 KB), same 32-wave occupancy as R2.

constexpr int K = 40;
constexpr int C = 3;
constexpr int F = 32;
constexpr float EPS = 1e-3f;
constexpr float DIST_SCALE = 10.0f;
constexpr int OUT_PER_V = F * C * C + F * C; // 384
constexpr int VPB = 8;                        // vertices per 256-thread block
constexpr int PAIRS = VPB * K;                // 320
constexpr int OUT_DW = VPB * OUT_PER_V;       // 3072 dwords staged per block
constexpr int OUT_F4 = OUT_DW / 4;            // 768 float4 per block

typedef float floatx4 __attribute__((ext_vector_type(4)));  // nt-store compatible

__global__ __launch_bounds__(256) void neighcov_kernel(
    const float* __restrict__ coords,    // V x 3
    const float* __restrict__ distsq,    // V x K
    const float* __restrict__ features,  // V x F
    const int*   __restrict__ nidx,      // V x K
    float* __restrict__ out,             // V x 384
    int V)
{
    __shared__ float4  s_wxyz[PAIRS];   // (w, x, y, z) per (v,k)
    __shared__ int     s_joff[PAIRS];   // j*F element offset into features
    __shared__ floatx4 s_out4[OUT_F4];  // staged output (16B-aligned)

    const int tid   = threadIdx.x;
    const int vbase = blockIdx.x * VPB;
    const long long total_pairs = (long long)V * K;

    // ---- Phase 1: stage weights/coords, 320 pairs, high MLP ----
    #pragma unroll
    for (int p = tid; p < PAIRS; p += 256) {
        const long long gp = (long long)vbase * K + p;
        int idx = -1;
        float d = 0.f;
        if (gp < total_pairs) {
            idx = __builtin_nontemporal_load(nidx + gp);    // coalesced, single-use
            d   = __builtin_nontemporal_load(distsq + gp);  // coalesced, single-use
        }
        const bool valid = (idx >= 0);
        const int j = valid ? idx : 0;
        const float w = valid ? __expf(-DIST_SCALE * d) : 0.f;
        const float x = coords[(size_t)j * 3 + 0];
        const float y = coords[(size_t)j * 3 + 1];
        const float z = coords[(size_t)j * 3 + 2];
        s_wxyz[p] = make_float4(w, x, y, z);
        s_joff[p] = j * F;
    }
    __syncthreads();

    // ---- Phase 2: one lane per (vertex, feature) ----
    const int f    = tid & (F - 1);
    const int vloc = tid >> 5;

    const float4* wp = &s_wxyz[vloc * K];
    const int*    jp = &s_joff[vloc * K];

    float wsum = 0.f;
    float m0 = 0.f, m1 = 0.f, m2 = 0.f;
    float s00 = 0.f, s01 = 0.f, s02 = 0.f, s11 = 0.f, s12 = 0.f, s22 = 0.f;

    #pragma unroll 8
    for (int k = 0; k < K; ++k) {
        const float4 q = wp[k];            // broadcast LDS read (no conflict)
        const int jo   = jp[k];            // broadcast LDS read
        const float feat = features[jo + f];  // coalesced 128B row gather
        const float fw = q.x * feat;       // w==0 encodes invalid neighbor
        const float x = q.y, y = q.z, z = q.w;
        const float fx = fw * x, fy = fw * y, fz = fw * z;
        wsum += fw;
        m0 += fx;        m1 += fy;        m2 += fz;
        s00 += fx * x;   s01 += fx * y;   s02 += fx * z;
        s11 += fy * y;   s12 += fy * z;   s22 += fz * z;
    }

    const float inv = 1.f / (wsum + EPS);
    const float mu0 = m0 * inv, mu1 = m1 * inv, mu2 = m2 * inv;
    const float c00 = s00 * inv - mu0 * mu0;
    const float c01 = s01 * inv - mu0 * mu1;
    const float c02 = s02 * inv - mu0 * mu2;
    const float c11 = s11 * inv - mu1 * mu1;
    const float c12 = s12 * inv - mu1 * mu2;
    const float c22 = s22 * inv - mu2 * mu2;

    // Stage results in LDS. Strides 9 and 3 are odd -> per-half-wave bank
    // permutation, 2 lanes/bank max (free).
    float* s_out = (float*)s_out4;
    float* so = s_out + vloc * OUT_PER_V + f * 9;
    so[0] = c00; so[1] = c01; so[2] = c02;
    so[3] = c01; so[4] = c11; so[5] = c12;
    so[6] = c02; so[7] = c12; so[8] = c22;
    float* sm = s_out + vloc * OUT_PER_V + F * 9 + f * 3;
    sm[0] = mu0; sm[1] = mu1; sm[2] = mu2;

    __syncthreads();

    // ---- Phase 3: coalesced non-temporal 16B writeback ----
    const int rem_v  = V - vbase;  // >= 1
    const int lim_f4 = (rem_v >= VPB) ? OUT_F4 : rem_v * (OUT_PER_V / 4);
    floatx4* o4 = (floatx4*)(out + (size_t)vbase * OUT_PER_V);
    #pragma unroll
    for (int g = tid; g < OUT_F4; g += 256) {
        if (g < lim_f4) {
            __builtin_nontemporal_store(s_out4[g], o4 + g);  // contiguous b128 LDS read, conflict-free
        }
    }
}

extern "C" void kernel_launch(void* const* d_in, const int* in_sizes, int n_in,
                              void* d_out, int out_size, void* d_ws, size_t ws_size,
                              hipStream_t stream) {
    const float* coords   = (const float*)d_in[0];
    const float* distsq   = (const float*)d_in[1];
    const float* features = (const float*)d_in[2];
    const int*   nidx     = (const int*)d_in[3];
    float* out = (float*)d_out;

    const int V = in_sizes[0] / C;            // coordinates is V x 3
    const int blocks = (V + VPB - 1) / VPB;   // 8 vertices per 256-thread block

    neighcov_kernel<<<blocks, 256, 0, stream>>>(coords, distsq, features, nidx, out, V);
}